// Round 1
// baseline (444.629 us; speedup 1.0000x reference)
//
#include <hip/hip_runtime.h>

#define NTHREADS 256
#define ROWLEN 16384
#define PER_THREAD 16   // uint4 per thread: 16 * 4 * 256 = 16384 floats

// Descending (suffix) bin selection over NB bins with 256 threads.
// Finds bin b such that count(bins > b) < krem <= count(bins >= b).
// Writes *sel_bin = b, *sel_rem = krem - count(bins > b).
template<int NB>
__device__ inline void select_bin(unsigned* hist, unsigned* wtot,
                                  unsigned* sel_bin, unsigned* sel_rem,
                                  unsigned tid, unsigned krem) {
  constexpr int BPT = NB / NTHREADS;
  const unsigned base = tid * BPT;
  unsigned c[BPT];
  unsigned s = 0;
#pragma unroll
  for (int i = 0; i < BPT; i++) { c[i] = hist[base + i]; s += c[i]; }

  const unsigned lane = tid & 63u;
  const unsigned wid  = tid >> 6;

  // inclusive suffix sum within the wave (sum over lanes >= lane)
  unsigned suf = s;
#pragma unroll
  for (int off = 1; off < 64; off <<= 1) {
    unsigned v = __shfl_down(suf, off);
    if (lane + off < 64) suf += v;
  }
  if (lane == 0) wtot[wid] = suf;   // wave total
  __syncthreads();

  // count of elements in bins strictly above this thread's range
  unsigned above = suf - s;
  for (unsigned w = wid + 1; w < 4; w++) above += wtot[w];

  // walk own bins from high to low; exactly one (thread,bin) crosses krem
#pragma unroll
  for (int i = BPT - 1; i >= 0; i--) {
    unsigned cc = c[i];
    if (above < krem && above + cc >= krem) {
      *sel_bin = base + (unsigned)i;
      *sel_rem = krem - above;
    }
    above += cc;
  }
  __syncthreads();
}

__global__ __launch_bounds__(NTHREADS)
void topk_act_kernel(const float* __restrict__ x, float* __restrict__ out,
                     const int* __restrict__ kp) {
  __shared__ unsigned hist[2048];
  __shared__ unsigned wtot[4];
  __shared__ unsigned sel_bin, sel_rem;

  const unsigned tid = threadIdx.x;
  const unsigned k = (unsigned)*kp;
  const size_t rowoff = (size_t)blockIdx.x * (size_t)ROWLEN;
  const uint4* __restrict__ xr  = reinterpret_cast<const uint4*>(x + rowoff);
  uint4* __restrict__ orow      = reinterpret_cast<uint4*>(out + rowoff);

  // load 64 floats/thread into registers, coalesced
  uint4 d[PER_THREAD];
#pragma unroll
  for (int j = 0; j < PER_THREAD; j++) d[j] = xr[tid + j * NTHREADS];

  // ---------- level 1: abs bits 20..30 (2048 bins) ----------
#pragma unroll
  for (int i = 0; i < 2048 / NTHREADS; i++) hist[tid + i * NTHREADS] = 0u;
  __syncthreads();
#pragma unroll
  for (int j = 0; j < PER_THREAD; j++) {
    atomicAdd(&hist[(d[j].x & 0x7fffffffu) >> 20], 1u);
    atomicAdd(&hist[(d[j].y & 0x7fffffffu) >> 20], 1u);
    atomicAdd(&hist[(d[j].z & 0x7fffffffu) >> 20], 1u);
    atomicAdd(&hist[(d[j].w & 0x7fffffffu) >> 20], 1u);
  }
  __syncthreads();
  select_bin<2048>(hist, wtot, &sel_bin, &sel_rem, tid, k);
  const unsigned P1 = sel_bin;
  const unsigned r1 = sel_rem;
  __syncthreads();

  // ---------- level 2: abs bits 10..19 (1024 bins), prefix P1 ----------
#pragma unroll
  for (int i = 0; i < 1024 / NTHREADS; i++) hist[tid + i * NTHREADS] = 0u;
  __syncthreads();
#pragma unroll
  for (int j = 0; j < PER_THREAD; j++) {
    unsigned u;
    u = d[j].x & 0x7fffffffu; if ((u >> 20) == P1) atomicAdd(&hist[(u >> 10) & 0x3FFu], 1u);
    u = d[j].y & 0x7fffffffu; if ((u >> 20) == P1) atomicAdd(&hist[(u >> 10) & 0x3FFu], 1u);
    u = d[j].z & 0x7fffffffu; if ((u >> 20) == P1) atomicAdd(&hist[(u >> 10) & 0x3FFu], 1u);
    u = d[j].w & 0x7fffffffu; if ((u >> 20) == P1) atomicAdd(&hist[(u >> 10) & 0x3FFu], 1u);
  }
  __syncthreads();
  select_bin<1024>(hist, wtot, &sel_bin, &sel_rem, tid, r1);
  const unsigned P12 = (P1 << 10) | sel_bin;
  const unsigned r2 = sel_rem;
  __syncthreads();

  // ---------- level 3: abs bits 0..9 (1024 bins), prefix P12 ----------
#pragma unroll
  for (int i = 0; i < 1024 / NTHREADS; i++) hist[tid + i * NTHREADS] = 0u;
  __syncthreads();
#pragma unroll
  for (int j = 0; j < PER_THREAD; j++) {
    unsigned u;
    u = d[j].x & 0x7fffffffu; if ((u >> 10) == P12) atomicAdd(&hist[u & 0x3FFu], 1u);
    u = d[j].y & 0x7fffffffu; if ((u >> 10) == P12) atomicAdd(&hist[u & 0x3FFu], 1u);
    u = d[j].z & 0x7fffffffu; if ((u >> 10) == P12) atomicAdd(&hist[u & 0x3FFu], 1u);
    u = d[j].w & 0x7fffffffu; if ((u >> 10) == P12) atomicAdd(&hist[u & 0x3FFu], 1u);
  }
  __syncthreads();
  select_bin<1024>(hist, wtot, &sel_bin, &sel_rem, tid, r2);
  const unsigned V = (P12 << 10) | sel_bin;   // k-th largest abs bit pattern

  // ---------- final: mask and write ----------
#pragma unroll
  for (int j = 0; j < PER_THREAD; j++) {
    uint4 o;
    o.x = ((d[j].x & 0x7fffffffu) >= V) ? d[j].x : 0u;
    o.y = ((d[j].y & 0x7fffffffu) >= V) ? d[j].y : 0u;
    o.z = ((d[j].z & 0x7fffffffu) >= V) ? d[j].z : 0u;
    o.w = ((d[j].w & 0x7fffffffu) >= V) ? d[j].w : 0u;
    orow[tid + j * NTHREADS] = o;
  }
}

extern "C" void kernel_launch(void* const* d_in, const int* in_sizes, int n_in,
                              void* d_out, int out_size, void* d_ws, size_t ws_size,
                              hipStream_t stream) {
  const float* x  = (const float*)d_in[0];
  const int*   kp = (const int*)d_in[1];
  float*       out = (float*)d_out;
  const int rows = out_size / ROWLEN;   // 4096
  topk_act_kernel<<<rows, NTHREADS, 0, stream>>>(x, out, kp);
}

// Round 2
// 442.987 us; speedup vs baseline: 1.0037x; 1.0037x over previous
//
#include <hip/hip_runtime.h>

#define NT 512
#define ROWLEN 16384
#define PT 8      // uint4 per thread: 8 * 4 * 512 = 16384 floats
#define CAP 4096  // candidate buffer entries (16 KB)

// Descending (suffix) bin selection over NB bins with NT threads.
// Finds bin b with count(bins > b) < krem <= count(bins >= b).
// sel[0] = b, sel[1] = krem - count(bins > b).
template<int NB>
__device__ inline void select_bin(unsigned* hist, unsigned* wtot,
                                  unsigned* sel, unsigned tid, unsigned krem) {
  constexpr int BPT = NB / NT;
  constexpr int NW = NT / 64;
  const unsigned base = tid * BPT;
  unsigned c[BPT];
  unsigned s = 0;
#pragma unroll
  for (int i = 0; i < BPT; i++) { c[i] = hist[base + i]; s += c[i]; }

  const unsigned lane = tid & 63u;
  const unsigned wid  = tid >> 6;

  // inclusive suffix sum within the wave (sum over lanes >= lane)
  unsigned suf = s;
#pragma unroll
  for (int off = 1; off < 64; off <<= 1) {
    unsigned v = __shfl_down(suf, off);
    if (lane + off < 64) suf += v;
  }
  if (lane == 0) wtot[wid] = suf;
  __syncthreads();

  unsigned above = suf - s;  // elements in higher bins within this wave
  for (unsigned w = wid + 1; w < NW; w++) above += wtot[w];

#pragma unroll
  for (int i = BPT - 1; i >= 0; i--) {
    unsigned cc = c[i];
    if (above < krem && above + cc >= krem) {
      sel[0] = base + (unsigned)i;
      sel[1] = krem - above;
    }
    above += cc;
  }
  __syncthreads();
}

__global__ __launch_bounds__(NT, 6)
void topk_act_kernel(const float* __restrict__ x, float* __restrict__ out,
                     const int* __restrict__ kp) {
  __shared__ unsigned hist1[2048];
  __shared__ unsigned hist2[1024];
  __shared__ unsigned hist3[1024];
  __shared__ unsigned cand[CAP];
  __shared__ unsigned wtot[NT / 64];
  __shared__ unsigned sel[2];
  __shared__ unsigned cnt;

  const unsigned tid = threadIdx.x;
  const unsigned k = (unsigned)*kp;
  const size_t rowoff = (size_t)blockIdx.x * (size_t)ROWLEN;
  const uint4* __restrict__ xr = reinterpret_cast<const uint4*>(x + rowoff);
  uint4* __restrict__ orow     = reinterpret_cast<uint4*>(out + rowoff);

  // coalesced load: 32 floats/thread in registers
  uint4 d[PT];
#pragma unroll
  for (int j = 0; j < PT; j++) d[j] = xr[tid + j * NT];

  // zero everything up front (single barrier covers all three hists)
#pragma unroll
  for (int i = 0; i < 2048 / NT; i++) hist1[tid + i * NT] = 0u;
#pragma unroll
  for (int i = 0; i < 1024 / NT; i++) hist2[tid + i * NT] = 0u;
#pragma unroll
  for (int i = 0; i < 1024 / NT; i++) hist3[tid + i * NT] = 0u;
  if (tid == 0) cnt = 0u;
  __syncthreads();

  // ---- level 1: 2048 bins over a>>21, where a = u<<1 (sign dropped) ----
#pragma unroll
  for (int j = 0; j < PT; j++) {
    atomicAdd(&hist1[(d[j].x << 1) >> 21], 1u);
    atomicAdd(&hist1[(d[j].y << 1) >> 21], 1u);
    atomicAdd(&hist1[(d[j].z << 1) >> 21], 1u);
    atomicAdd(&hist1[(d[j].w << 1) >> 21], 1u);
  }
  __syncthreads();
  select_bin<2048>(hist1, wtot, sel, tid, k);
  const unsigned P1 = sel[0];
  const unsigned r1 = sel[1];

  // ---- gather candidates (elements whose level-1 bin == P1) ----
#pragma unroll
  for (int j = 0; j < PT; j++) {
    unsigned a;
    a = d[j].x << 1; if ((a >> 21) == P1) { unsigned i = atomicAdd(&cnt, 1u); if (i < CAP) cand[i] = a; }
    a = d[j].y << 1; if ((a >> 21) == P1) { unsigned i = atomicAdd(&cnt, 1u); if (i < CAP) cand[i] = a; }
    a = d[j].z << 1; if ((a >> 21) == P1) { unsigned i = atomicAdd(&cnt, 1u); if (i < CAP) cand[i] = a; }
    a = d[j].w << 1; if ((a >> 21) == P1) { unsigned i = atomicAdd(&cnt, 1u); if (i < CAP) cand[i] = a; }
  }
  __syncthreads();
  const unsigned n = cnt;

  // ---- level 2: bins over bits (a>>11)&0x3FF ----
  if (n <= CAP) {
    for (unsigned i = tid; i < n; i += NT)
      atomicAdd(&hist2[(cand[i] >> 11) & 0x3FFu], 1u);
  } else {  // overflow fallback: full register scan
#pragma unroll
    for (int j = 0; j < PT; j++) {
      unsigned a;
      a = d[j].x << 1; if ((a >> 21) == P1) atomicAdd(&hist2[(a >> 11) & 0x3FFu], 1u);
      a = d[j].y << 1; if ((a >> 21) == P1) atomicAdd(&hist2[(a >> 11) & 0x3FFu], 1u);
      a = d[j].z << 1; if ((a >> 21) == P1) atomicAdd(&hist2[(a >> 11) & 0x3FFu], 1u);
      a = d[j].w << 1; if ((a >> 21) == P1) atomicAdd(&hist2[(a >> 11) & 0x3FFu], 1u);
    }
  }
  __syncthreads();
  select_bin<1024>(hist2, wtot, sel, tid, r1);
  const unsigned P2 = sel[0];
  const unsigned r2 = sel[1];

  // ---- level 3: bins over bits (a>>1)&0x3FF ----
  if (n <= CAP) {
    for (unsigned i = tid; i < n; i += NT) {
      unsigned a = cand[i];
      if (((a >> 11) & 0x3FFu) == P2) atomicAdd(&hist3[(a >> 1) & 0x3FFu], 1u);
    }
  } else {
    const unsigned P12 = (P1 << 10) | P2;
#pragma unroll
    for (int j = 0; j < PT; j++) {
      unsigned a;
      a = d[j].x << 1; if ((a >> 11) == P12) atomicAdd(&hist3[(a >> 1) & 0x3FFu], 1u);
      a = d[j].y << 1; if ((a >> 11) == P12) atomicAdd(&hist3[(a >> 1) & 0x3FFu], 1u);
      a = d[j].z << 1; if ((a >> 11) == P12) atomicAdd(&hist3[(a >> 1) & 0x3FFu], 1u);
      a = d[j].w << 1; if ((a >> 11) == P12) atomicAdd(&hist3[(a >> 1) & 0x3FFu], 1u);
    }
  }
  __syncthreads();
  select_bin<1024>(hist3, wtot, sel, tid, r2);
  const unsigned Va = (P1 << 21) | (P2 << 11) | (sel[0] << 1);  // k-th largest, in a-space

  // ---- final: mask and write ----
#pragma unroll
  for (int j = 0; j < PT; j++) {
    uint4 o;
    o.x = ((d[j].x << 1) >= Va) ? d[j].x : 0u;
    o.y = ((d[j].y << 1) >= Va) ? d[j].y : 0u;
    o.z = ((d[j].z << 1) >= Va) ? d[j].z : 0u;
    o.w = ((d[j].w << 1) >= Va) ? d[j].w : 0u;
    orow[tid + j * NT] = o;
  }
}

extern "C" void kernel_launch(void* const* d_in, const int* in_sizes, int n_in,
                              void* d_out, int out_size, void* d_ws, size_t ws_size,
                              hipStream_t stream) {
  const float* x   = (const float*)d_in[0];
  const int*   kp  = (const int*)d_in[1];
  float*       out = (float*)d_out;
  const int rows = out_size / ROWLEN;  // 4096
  topk_act_kernel<<<rows, NT, 0, stream>>>(x, out, kp);
}